// Round 6
// baseline (1900.340 us; speedup 1.0000x reference)
//
#include <hip/hip_runtime.h>
#include <cstdint>
#include <cstddef>

#define NG     1000
#define NPER   100
#define EPER   1600
#define NNODES (NG*NPER)
#define NEDGES (NG*EPER)
#define HID    128
#define LAT    385
#define FST    388   // padded f32 row stride for top rows (float4-aligned)
#define KTOP   40
#define CHG    250   // graphs per chunk
#define NCHUNK 4

// ---------------- preprocessing ----------------
__global__ void k_deg(const int* __restrict__ dst, int* __restrict__ deg) {
  int e = blockIdx.x*blockDim.x + threadIdx.x;
  if (e < NEDGES) atomicAdd(&deg[dst[e]], 1);
}

__global__ void k_dinv64(const int* __restrict__ deg, double* __restrict__ dinv) {
  int i = blockIdx.x*blockDim.x + threadIdx.x;
  if (i < NNODES) {
    int d = deg[i];
    dinv[i] = (d > 0) ? 1.0/sqrt((double)d) : 0.0;
  }
}

__global__ __launch_bounds__(128)
void k_csr(const int* __restrict__ ei0, const int* __restrict__ ei1,
           const int* __restrict__ deg,
           int* __restrict__ rowstart, int* __restrict__ csr_s) {
  int g = blockIdx.x;
  int t = threadIdx.x;
  __shared__ int lstart[NPER];
  __shared__ int cursor[NPER];
  __shared__ int ldeg[NPER];
  if (t < NPER) ldeg[t] = deg[g*NPER + t];
  __syncthreads();
  if (t == 0) {
    int run = 0;
    for (int i = 0; i < NPER; ++i) { lstart[i] = run; run += ldeg[i]; }
  }
  __syncthreads();
  if (t < NPER) { rowstart[g*NPER + t] = lstart[t]; cursor[t] = lstart[t]; }
  __syncthreads();
  for (int e = t; e < EPER; e += 128) {
    int ge = g*EPER + e;
    int s = ei0[ge], d = ei1[ge];
    int slot = atomicAdd(&cursor[d - g*NPER], 1);
    csr_s[(size_t)g*EPER + slot] = s - g*NPER;
  }
}

// ---------------- GCN layer in f64, chunked (64 out-channels per block.y) -------
// grid (CHG, 2), block 256: cp = ch-pair (0..31), ng = node group (0..7),
// 13 nodes per group (8*13 = 104 >= 100). h buffers are chunk-local [CHG*NPER][128].
template<bool L0>
__global__ __launch_bounds__(256)
void k_layer64(const double* __restrict__ h_in,
               const int* __restrict__ z, const float* __restrict__ ztab,
               const float* __restrict__ x,
               const float* __restrict__ W, const float* __restrict__ b,
               const int* __restrict__ rowstart, const int* __restrict__ csr_s,
               const double* __restrict__ dinv,
               double* __restrict__ h_out, int gofs) {
  int gl   = blockIdx.x;          // chunk-local graph
  int g    = gofs + gl;           // global graph
  int half = blockIdx.y;
  int t    = threadIdx.x;
  int cp   = t & 31;
  int ng   = t >> 5;
  int c0   = half*64 + cp*2;

  __shared__ double hW[104][64];   // 53,248 B
  __shared__ double dinvL[NPER];   //    800 B

  if (t < NPER) dinvL[t] = dinv[g*NPER + t];

  double accx[13], accy[13];
  #pragma unroll
  for (int i = 0; i < 13; ++i) { accx[i] = 0.0; accy[i] = 0.0; }

  int nodeid[13];
  #pragma unroll
  for (int i = 0; i < 13; ++i) {
    int n = ng + 8*i;
    nodeid[i] = (n < NPER) ? n : (NPER-1);
  }

  // ---- phase A: 128 input channels (ztab for L0, previous layer otherwise) ----
  {
    const double* rp[13];
    const float*  rpf[13];
    #pragma unroll
    for (int i = 0; i < 13; ++i) {
      if (L0) rpf[i] = ztab + (size_t)z[g*NPER + nodeid[i]]*HID;
      else    rp[i]  = h_in + (size_t)(gl*NPER + nodeid[i])*HID;
    }
    for (int k = 0; k < 128; k += 2) {
      float2 wa = *(const float2*)&W[(k  )*HID + c0];
      float2 wb = *(const float2*)&W[(k+1)*HID + c0];
      double wa0 = (double)wa.x, wa1 = (double)wa.y;
      double wb0 = (double)wb.x, wb1 = (double)wb.y;
      #pragma unroll
      for (int i = 0; i < 13; ++i) {
        double h0, h1;
        if (L0) { float2 hf = *(const float2*)&rpf[i][k]; h0 = (double)hf.x; h1 = (double)hf.y; }
        else    { double2 hd = *(const double2*)&rp[i][k]; h0 = hd.x; h1 = hd.y; }
        accx[i] = fma(h0, wa0, accx[i]); accx[i] = fma(h1, wb0, accx[i]);
        accy[i] = fma(h0, wa1, accy[i]); accy[i] = fma(h1, wb1, accy[i]);
      }
    }
  }
  // ---- phase B (layer 0 only): x with W rows 128..255 ----
  if (L0) {
    const float* rpf[13];
    #pragma unroll
    for (int i = 0; i < 13; ++i)
      rpf[i] = x + (size_t)(g*NPER + nodeid[i])*HID;
    const float* Wx = W + 128*HID;
    for (int k = 0; k < 128; k += 2) {
      float2 wa = *(const float2*)&Wx[(k  )*HID + c0];
      float2 wb = *(const float2*)&Wx[(k+1)*HID + c0];
      double wa0 = (double)wa.x, wa1 = (double)wa.y;
      double wb0 = (double)wb.x, wb1 = (double)wb.y;
      #pragma unroll
      for (int i = 0; i < 13; ++i) {
        float2 hf = *(const float2*)&rpf[i][k];
        double h0 = (double)hf.x, h1 = (double)hf.y;
        accx[i] = fma(h0, wa0, accx[i]); accx[i] = fma(h1, wb0, accx[i]);
        accy[i] = fma(h0, wa1, accy[i]); accy[i] = fma(h1, wb1, accy[i]);
      }
    }
  }
  #pragma unroll
  for (int i = 0; i < 13; ++i) {
    int n = ng + 8*i;
    hW[n][cp*2]   = accx[i];
    hW[n][cp*2+1] = accy[i];
  }
  __syncthreads();

  // ---- aggregation: out[dst] = tanh(sum_e dinv[s]*dinv[d]*hW[src] + b), f64 ----
  double bx = (double)b[c0], by = (double)b[c0+1];
  #pragma unroll 1
  for (int i = 0; i < 13; ++i) {
    int n = ng + 8*i;
    if (n < NPER) {
      int gn = g*NPER + n;
      int s0 = rowstart[gn];
      int e1 = (n == NPER-1) ? EPER : rowstart[gn+1];
      double dd = dinvL[n];
      double sx = 0.0, sy = 0.0;
      for (int e = s0; e < e1; ++e) {
        int    s  = csr_s[(size_t)g*EPER + e];
        double nm = dinvL[s]*dd;
        sx = fma(nm, hW[s][cp*2],   sx);
        sy = fma(nm, hW[s][cp*2+1], sy);
      }
      size_t o = (size_t)(gl*NPER + n)*HID + c0;
      h_out[o]   = tanh(sx + bx);
      h_out[o+1] = tanh(sy + by);
    }
  }
}

// ---------------- layer 3 (COUT=1) f64 + sort-pool rank selection, chunked --------
__global__ __launch_bounds__(128)
void k_l3sel(const double* __restrict__ h2, const float* __restrict__ W3,
             const float* __restrict__ b3,
             const int* __restrict__ rowstart, const int* __restrict__ csr_s,
             const double* __restrict__ dinv,
             double* __restrict__ key64, int* __restrict__ sel, int gofs) {
  int gl = blockIdx.x, g = gofs + gl, t = threadIdx.x;
  __shared__ double w3d[128];
  __shared__ double hv[NPER];
  __shared__ double key[NPER];
  __shared__ double dinvL[NPER];
  if (t < 128) w3d[t] = (double)W3[t];
  if (t < NPER) dinvL[t] = dinv[g*NPER + t];
  __syncthreads();
  if (t < NPER) {
    const double* row = h2 + (size_t)(gl*NPER + t)*HID;
    double s = 0.0;
    for (int k = 0; k < 128; ++k) s = fma(row[k], w3d[k], s);
    hv[t] = s;
  }
  __syncthreads();
  if (t < NPER) {
    int gn = g*NPER + t;
    int s0 = rowstart[gn];
    int e1 = (t == NPER-1) ? EPER : rowstart[gn+1];
    double dd = dinvL[t];
    double sum = 0.0;
    for (int e = s0; e < e1; ++e) {
      int s = csr_s[(size_t)g*EPER + e];
      sum = fma(dinvL[s]*dd, hv[s], sum);
    }
    double kv = tanh(sum + (double)b3[0]);
    key[t] = kv;
    key64[gl*NPER + t] = kv;
  }
  __syncthreads();
  // stable descending rank == jnp.argsort(-key) with index tie-break
  if (t < NPER) {
    double ki = key[t];
    int rank = 0;
    for (int j = 0; j < NPER; ++j) {
      double kj = key[j];
      rank += ((kj > ki) || (kj == ki && j < t)) ? 1 : 0;
    }
    if (rank < KTOP) sel[g*KTOP + rank] = g*NPER + t;
  }
}

// ---------------- gather top-K rows -> compact f32 [NG][KTOP][FST] ---------------
__global__ __launch_bounds__(256)
void k_gather(const double* __restrict__ h0, const double* __restrict__ h1,
              const double* __restrict__ h2, const double* __restrict__ key64,
              const int* __restrict__ sel, float* __restrict__ topf, int gofs) {
  int gl = blockIdx.x, g = gofs + gl, t = threadIdx.x;
  for (int idx = t; idx < KTOP*97; idx += 256) {
    int k = idx / 97, q = idx - k*97;
    int nloc = sel[g*KTOP + k] - g*NPER;      // 0..99
    size_t row = (size_t)(gl*NPER + nloc)*HID;
    float4 v;
    if (q < 96) {
      const double* src = (q < 32) ? &h0[row + q*4]
                        : (q < 64) ? &h1[row + (q-32)*4]
                                   : &h2[row + (q-64)*4];
      double2 a = *(const double2*)src;
      double2 c = *(const double2*)(src + 2);
      v = make_float4((float)a.x, (float)a.y, (float)c.x, (float)c.y);
    } else {
      v = make_float4((float)key64[gl*NPER + nloc], 0.f, 0.f, 0.f);
    }
    *(float4*)&topf[((size_t)g*KTOP + k)*FST + q*4] = v;
  }
}

// ---------------- head: conv1 + pool + conv2 + MLP ------------------------------
__global__ __launch_bounds__(256)
void k_head(const float* __restrict__ topf,
            const float* __restrict__ cw1, const float* __restrict__ cb1,
            const float* __restrict__ cw2, const float* __restrict__ cb2,
            const float* __restrict__ mW1, const float* __restrict__ mb1,
            const float* __restrict__ mW2, const float* __restrict__ mb2,
            float* __restrict__ out) {
  int g = blockIdx.x, t = threadIdx.x;
  __shared__ float4 top4[KTOP*97];   // 62,080 B
  __shared__ float  c1t[LAT*16];     // 24,640 B (cw1 transposed: [l][f])
  __shared__ float  y1s[16*KTOP];
  __shared__ float  pools[16*20];
  __shared__ float  y2s[512];
  __shared__ float  m1s[128];
  float* top = (float*)top4;

  const float4* tp = (const float4*)topf;
  for (int idx = t; idx < KTOP*97; idx += 256)
    top4[idx] = tp[(size_t)g*KTOP*97 + idx];
  for (int idx = t; idx < LAT*16; idx += 256) {
    int l = idx >> 4, f = idx & 15;
    c1t[idx] = cw1[f*LAT + l];
  }
  __syncthreads();
  // conv1 (kernel=stride=LAT): y1[f][k] = relu(dot(cw1[f], top[k]) + cb1[f])
  for (int idx = t; idx < 16*KTOP; idx += 256) {
    int f = idx & 15, k = idx >> 4;
    float acc = cb1[f];
    for (int l = 0; l < LAT; ++l)
      acc = fmaf(top[k*FST + l], c1t[l*16 + f], acc);
    y1s[f*KTOP + k] = fmaxf(acc, 0.f);
  }
  __syncthreads();
  for (int idx = t; idx < 16*20; idx += 256) {
    int f = idx / 20, tt = idx % 20;
    pools[idx] = fmaxf(y1s[f*KTOP + 2*tt], y1s[f*KTOP + 2*tt + 1]);
  }
  __syncthreads();
  for (int idx = t; idx < 512; idx += 256) {
    int c = idx >> 4, tt = idx & 15;
    float acc = cb2[c];
    #pragma unroll
    for (int f = 0; f < 16; ++f)
      #pragma unroll
      for (int j = 0; j < 5; ++j)
        acc = fmaf(cw2[c*80 + f*5 + j], pools[f*20 + tt + j], acc);
    y2s[idx] = fmaxf(acc, 0.f);
  }
  __syncthreads();
  if (t < 128) {
    float acc = mb1[t];
    for (int i = 0; i < 512; ++i)
      acc = fmaf(y2s[i], mW1[i*128 + t], acc);
    m1s[t] = fmaxf(acc, 0.f);
  }
  __syncthreads();
  if (t < 64) {
    float v = fmaf(m1s[t], mW2[t], m1s[t+64]*mW2[t+64]);
    #pragma unroll
    for (int off = 32; off > 0; off >>= 1) v += __shfl_down(v, off);
    if (t == 0) out[g] = v + mb2[0];
  }
}

// ---------------- launch ----------------
extern "C" void kernel_launch(void* const* d_in, const int* in_sizes, int n_in,
                              void* d_out, int out_size, void* d_ws, size_t ws_size,
                              hipStream_t stream) {
  const float* x    = (const float*)d_in[0];
  const int*   z    = (const int*)  d_in[1];
  const int*   ei   = (const int*)  d_in[2];
  // d_in[3] = batch (unused; graphs are contiguous by construction)
  const float* ztab = (const float*)d_in[4];
  const float* W0   = (const float*)d_in[5];
  const float* b0   = (const float*)d_in[6];
  const float* W1   = (const float*)d_in[7];
  const float* b1   = (const float*)d_in[8];
  const float* W2   = (const float*)d_in[9];
  const float* b2   = (const float*)d_in[10];
  const float* W3   = (const float*)d_in[11];
  const float* b3   = (const float*)d_in[12];
  const float* cw1  = (const float*)d_in[13];
  const float* cb1  = (const float*)d_in[14];
  const float* cw2  = (const float*)d_in[15];
  const float* cb2  = (const float*)d_in[16];
  const float* mW1  = (const float*)d_in[17];
  const float* mb1  = (const float*)d_in[18];
  const float* mW2  = (const float*)d_in[19];
  const float* mb2  = (const float*)d_in[20];
  float* out = (float*)d_out;

  char* ws = (char*)d_ws;
  size_t off = 0;
  auto alloc = [&](size_t bytes) {
    void* p = ws + off;
    off = (off + bytes + 255) & ~(size_t)255;
    return p;
  };
  int*    deg      = (int*)   alloc((size_t)NNODES*4);          //  0.4 MB
  double* dinv     = (double*)alloc((size_t)NNODES*8);          //  0.8 MB
  int*    rowstart = (int*)   alloc((size_t)NNODES*4);          //  0.4 MB
  int*    csr_s    = (int*)   alloc((size_t)NEDGES*4);          //  6.4 MB
  int*    sel      = (int*)   alloc((size_t)NG*KTOP*4);         //  0.16 MB
  double* key64    = (double*)alloc((size_t)CHG*NPER*8);        //  0.2 MB
  double* h0       = (double*)alloc((size_t)CHG*NPER*HID*8);    // 25.6 MB
  double* h1       = (double*)alloc((size_t)CHG*NPER*HID*8);    // 25.6 MB
  double* h2       = (double*)alloc((size_t)CHG*NPER*HID*8);    // 25.6 MB
  float*  topf     = (float*) alloc((size_t)NG*KTOP*FST*4);     // 62.1 MB
  (void)ws_size;                                                // ~148 MB total

  const int* ei0 = ei;            // src
  const int* ei1 = ei + NEDGES;   // dst

  hipMemsetAsync(deg, 0, (size_t)NNODES*4, stream);
  k_deg   <<<(NEDGES+255)/256, 256, 0, stream>>>(ei1, deg);
  k_dinv64<<<(NNODES+255)/256, 256, 0, stream>>>(deg, dinv);
  k_csr   <<<NG, 128, 0, stream>>>(ei0, ei1, deg, rowstart, csr_s);

  for (int c = 0; c < NCHUNK; ++c) {
    int gofs = c*CHG;
    dim3 lg(CHG, 2);
    k_layer64<true ><<<lg, 256, 0, stream>>>(h0, z, ztab, x, W0, b0, rowstart, csr_s, dinv, h0, gofs);
    k_layer64<false><<<lg, 256, 0, stream>>>(h0, z, ztab, x, W1, b1, rowstart, csr_s, dinv, h1, gofs);
    k_layer64<false><<<lg, 256, 0, stream>>>(h1, z, ztab, x, W2, b2, rowstart, csr_s, dinv, h2, gofs);
    k_l3sel<<<CHG, 128, 0, stream>>>(h2, W3, b3, rowstart, csr_s, dinv, key64, sel, gofs);
    k_gather<<<CHG, 256, 0, stream>>>(h0, h1, h2, key64, sel, topf, gofs);
  }
  k_head<<<NG, 256, 0, stream>>>(topf, cw1, cb1, cw2, cb2, mW1, mb1, mW2, mb2, out);
}